// Round 8
// baseline (859.172 us; speedup 1.0000x reference)
//
#include <hip/hip_runtime.h>
#include <math.h>

// ROIAlign FPN, LDS-window-staged channel loop.
// Block = (proposal n, channel-half cs): 256 threads = 16x16 padded sample
// grid (14x14 active). The ROI's bounding feature window (rows ymin..ymax,
// cols xv0..xv13+1) is staged into LDS with coalesced row loads for `cps`
// channels at a time; taps then read from LDS. Window area < ~1000 floats
// (scaled ROI area < 784 px), so 16KB LDS stages >= 4 channels per barrier
// pair. Grid = 1024 * 2 = 2048 blocks, 8 blocks/CU.

#define CSPLIT 2
#define CPB (256 / CSPLIT)      // channels per block = 128
#define LDS_FLOATS 4096         // 16 KB

__global__ __launch_bounds__(256) void roialign_stage_kernel(
    const float* __restrict__ f0, const float* __restrict__ f1,
    const float* __restrict__ f2, const float* __restrict__ f3,
    const float* __restrict__ props, float* __restrict__ out)
{
    __shared__ float S[LDS_FLOATS];

    const int blk = blockIdx.x;          // n*CSPLIT + cs
    const int cs  = blk & (CSPLIT - 1);
    const int n   = blk >> 1;            // 0..1023
    const int b   = n >> 9;              // image 0..1

    const int tid  = threadIdx.x;
    const int lane = tid & 63;
    const int wv   = tid >> 6;           // wave 0..3
    const int sx   = tid & 15;           // sample col 0..15 (14 active)
    const int sy   = tid >> 4;           // sample row 0..15 (14 active)
    const float rx = (float)min(sx, 13);
    const float ry = (float)min(sy, 13);

    // proposal (block-uniform -> scalar path)
    const float px1 = props[n * 4 + 0];
    const float py1 = props[n * 4 + 1];
    const float px2 = props[n * 4 + 2];
    const float py2 = props[n * 4 + 3];
    const float area = (px2 - px1) * (py2 - py1);
    float lf = floorf(2.0f + log2f(sqrtf(area) / 224.0f));
    lf = fminf(fmaxf(lf, 0.0f), 3.0f);
    const int lvl = (int)lf;

    const float* feat;
    int W;
    float scale;
    if (lvl == 0)      { feat = f0; W = 256; scale = 0.25f;    }
    else if (lvl == 1) { feat = f1; W = 128; scale = 0.125f;   }
    else if (lvl == 2) { feat = f2; W = 64;  scale = 0.0625f;  }
    else               { feat = f3; W = 32;  scale = 0.03125f; }

    // scaled proposal + sampling units (identical expressions to prior rounds)
    const float sx1f = px1 * scale;
    const float sy1f = py1 * scale;
    const float sx2f = px2 * scale;
    const float sy2f = py2 * scale;
    const float w_unit = (sx2f - sx1f) / 14.0f;
    const float h_unit = (sy2f - sy1f) / 14.0f;
    const float Wm1 = (float)(W - 1);

    // per-thread x geometry
    const float fx = rx * w_unit + w_unit * 0.5f + sx1f;
    int x0 = (int)floorf(fx);
    const float xc = fminf(fmaxf(fx, 0.0f), Wm1);
    int x0c = min(max(x0, 0), W - 1);
    int x1c = min(max(x0 + 1, 0), W - 1);
    const float wx0 = (float)x1c - xc;
    const float wx1 = xc - (float)x0c;
    const int xv = min(x0c, W - 2);      // when x0c==W-1 both weights are 0

    // per-thread y geometry
    const float fy = ry * h_unit + h_unit * 0.5f + sy1f;
    int y0 = (int)floorf(fy);
    const float yc = fminf(fmaxf(fy, 0.0f), Wm1);
    int y0c = min(max(y0, 0), W - 1);
    int y1c = min(max(y0 + 1, 0), W - 1);
    const float wy0 = (float)y1c - yc;
    const float wy1 = yc - (float)y0c;

    // block-uniform window bounds (same formulas at rx=0 / rx=13, ry=0 / ry=13;
    // geometry is monotone in rx/ry so all per-thread taps fall inside)
    const float fx_0  = 0.0f  * w_unit + w_unit * 0.5f + sx1f;
    const float fx_13 = 13.0f * w_unit + w_unit * 0.5f + sx1f;
    const int xv0  = min(min(max((int)floorf(fx_0),  0), W - 1), W - 2);
    const int xv13 = min(min(max((int)floorf(fx_13), 0), W - 1), W - 2);
    const int w_win = xv13 + 1 - xv0 + 1;          // cols xv0 .. xv13+1
    const float fy_0  = 0.0f  * h_unit + h_unit * 0.5f + sy1f;
    const float fy_13 = 13.0f * h_unit + h_unit * 0.5f + sy1f;
    const int ymin = min(max((int)floorf(fy_0), 0), W - 1);
    const int ymax = min(max((int)floorf(fy_13) + 1, 0), W - 1);
    const int h_win = ymax - ymin + 1;
    const int P = h_win * w_win;                   // < ~1000 by construction
    int cps = LDS_FLOATS / P;
    if (cps > CPB) cps = CPB;

    // per-thread LDS tap offsets
    const int loff00 = (y0c - ymin) * w_win + (xv - xv0);
    const int loff10 = (y1c - ymin) * w_win + (xv - xv0);

    const int WW = W * W;
    const int c0 = cs * CPB;
    const float* fb = feat + ((size_t)b * 256 + (size_t)c0) * (size_t)WW;
    const float* fwin = fb + (size_t)ymin * (size_t)W + (size_t)xv0;

    const bool active = (((sx | sy) & 1) == 0) && sx < 14 && sy < 14;
    float* outp = out + (size_t)(n * 256 + c0) * 49
                      + (size_t)(sy >> 1) * 7 + (size_t)(sx >> 1);

    for (int c0s = 0; c0s < CPB; c0s += cps) {
        const int cc = min(cps, CPB - c0s);

        // ---- stage cc channel windows into LDS (coalesced row loads) ----
        {
            int ch = 0, row = wv;
            while (row >= h_win) { row -= h_win; ++ch; }
            for (int rr = wv; rr < cc * h_win; rr += 4) {
                const float* src = fwin + (size_t)(c0s + ch) * (size_t)WW
                                        + (size_t)row * (size_t)W;
                float* dst = S + ch * P + row * w_win;
                for (int col = lane; col < w_win; col += 64)
                    dst[col] = src[col];
                row += 4;
                while (row >= h_win) { row -= h_win; ++ch; }
            }
        }
        __syncthreads();

        // ---- consume: taps from LDS, pool, store ----
        for (int j = 0; j < cc; ++j) {
            const int base = j * P;
            const float a0 = S[base + loff00];
            const float a1 = S[base + loff00 + 1];
            const float b0 = S[base + loff10];
            const float b1 = S[base + loff10 + 1];

            float v = wy0 * (wx0 * a0 + wx1 * a1)
                    + wy1 * (wx0 * b0 + wx1 * b1);

            v = fmaxf(v, __shfl_xor(v, 1));    // sx pair
            v = fmaxf(v, __shfl_xor(v, 16));   // sy pair

            if (active) outp[(size_t)(c0s + j) * 49] = v;
        }
        __syncthreads();
    }
}

extern "C" void kernel_launch(void* const* d_in, const int* in_sizes, int n_in,
                              void* d_out, int out_size, void* d_ws, size_t ws_size,
                              hipStream_t stream) {
    const float* f0 = (const float*)d_in[0];
    const float* f1 = (const float*)d_in[1];
    const float* f2 = (const float*)d_in[2];
    const float* f3 = (const float*)d_in[3];
    const float* props = (const float*)d_in[4];
    float* out = (float*)d_out;

    dim3 grid(1024 * CSPLIT), block(256);
    hipLaunchKernelGGL(roialign_stage_kernel, grid, block, 0, stream,
                       f0, f1, f2, f3, props, out);
}

// Round 9
// 74.922 us; speedup vs baseline: 11.4676x; 11.4676x over previous
//
#include <hip/hip_runtime.h>
#include <math.h>

// ROIAlign FPN, channel-loop layout, explicit 8-wide load batching.
// Block = (proposal n, channel-eighth cs): 256 threads = 16x16 padded sample
// grid (14x14 active). Geometry once per thread; channel loop in batches of 8:
// issue 16 float2 gathers, then consume (bilinear + shfl-pool + store).
// Grid = 1024 * 8 = 8192 blocks.

#define CSPLIT 8
#define CPB (256 / CSPLIT)   // channels per block = 32
#define BATCH 8

__global__ __launch_bounds__(256) void roialign_chan_kernel(
    const float* __restrict__ f0, const float* __restrict__ f1,
    const float* __restrict__ f2, const float* __restrict__ f3,
    const float* __restrict__ props, float* __restrict__ out)
{
    const int blk = blockIdx.x;          // n*CSPLIT + cs
    const int cs  = blk & (CSPLIT - 1);
    const int n   = blk >> 3;            // 0..1023
    const int b   = n >> 9;              // image 0..1

    const int tid = threadIdx.x;
    const int sx  = tid & 15;            // sample col 0..15 (14 active)
    const int sy  = tid >> 4;            // sample row 0..15 (14 active)
    const float rx = (float)min(sx, 13);
    const float ry = (float)min(sy, 13);

    // proposal (block-uniform -> scalar path)
    const float px1 = props[n * 4 + 0];
    const float py1 = props[n * 4 + 1];
    const float px2 = props[n * 4 + 2];
    const float py2 = props[n * 4 + 3];
    const float area = (px2 - px1) * (py2 - py1);
    float lf = floorf(2.0f + log2f(sqrtf(area) / 224.0f));
    lf = fminf(fmaxf(lf, 0.0f), 3.0f);
    const int lvl = (int)lf;

    const float* feat;
    int W;
    float scale;
    if (lvl == 0)      { feat = f0; W = 256; scale = 0.25f;    }
    else if (lvl == 1) { feat = f1; W = 128; scale = 0.125f;   }
    else if (lvl == 2) { feat = f2; W = 64;  scale = 0.0625f;  }
    else               { feat = f3; W = 32;  scale = 0.03125f; }

    // scaled proposal + sampling units (identical expressions to prior rounds)
    const float sx1f = px1 * scale;
    const float sy1f = py1 * scale;
    const float sx2f = px2 * scale;
    const float sy2f = py2 * scale;
    const float w_unit = (sx2f - sx1f) / 14.0f;
    const float h_unit = (sy2f - sy1f) / 14.0f;
    const float Wm1 = (float)(W - 1);

    // x geometry
    const float fx = rx * w_unit + w_unit * 0.5f + sx1f;
    int x0 = (int)floorf(fx);
    const float xc = fminf(fmaxf(fx, 0.0f), Wm1);
    int x0c = min(max(x0, 0), W - 1);
    int x1c = min(max(x0 + 1, 0), W - 1);
    const float wx0 = (float)x1c - xc;
    const float wx1 = xc - (float)x0c;
    const int xv = min(x0c, W - 2);      // when x0c==W-1 both weights are 0

    // y geometry
    const float fy = ry * h_unit + h_unit * 0.5f + sy1f;
    int y0 = (int)floorf(fy);
    const float yc = fminf(fmaxf(fy, 0.0f), Wm1);
    int y0c = min(max(y0, 0), W - 1);
    int y1c = min(max(y0 + 1, 0), W - 1);
    const float wy0 = (float)y1c - yc;
    const float wy1 = yc - (float)y0c;

    // per-lane tap offsets (channel-invariant), 32-bit
    const int off00 = y0c * W + xv;      // row y0c, cols xv, xv+1
    const int off10 = y1c * W + xv;      // row y1c
    const int WW = W * W;

    const int c0 = cs * CPB;
    const float* fb = feat + ((size_t)b * 256 + (size_t)c0) * (size_t)WW;

    const bool active = (((sx | sy) & 1) == 0) && sx < 14 && sy < 14;
    float* outp = out + (size_t)(n * 256 + c0) * 49
                      + (size_t)(sy >> 1) * 7 + (size_t)(sx >> 1);

    for (int cb = 0; cb < CPB; cb += BATCH) {
        float2 A[BATCH], Bv[BATCH];
        // phase 1: issue all 16 loads (no consumer between them)
        #pragma unroll
        for (int k = 0; k < BATCH; ++k) {
            const float* p = fb + (size_t)(cb + k) * (size_t)WW;
            A[k]  = *reinterpret_cast<const float2*>(p + off00);
            Bv[k] = *reinterpret_cast<const float2*>(p + off10);
        }
        // phase 2: consume
        #pragma unroll
        for (int k = 0; k < BATCH; ++k) {
            float v = wy0 * (wx0 * A[k].x  + wx1 * A[k].y)
                    + wy1 * (wx0 * Bv[k].x + wx1 * Bv[k].y);
            v = fmaxf(v, __shfl_xor(v, 1));    // sx pair
            v = fmaxf(v, __shfl_xor(v, 16));   // sy pair
            if (active) outp[(size_t)(cb + k) * 49] = v;
        }
    }
}

extern "C" void kernel_launch(void* const* d_in, const int* in_sizes, int n_in,
                              void* d_out, int out_size, void* d_ws, size_t ws_size,
                              hipStream_t stream) {
    const float* f0 = (const float*)d_in[0];
    const float* f1 = (const float*)d_in[1];
    const float* f2 = (const float*)d_in[2];
    const float* f3 = (const float*)d_in[3];
    const float* props = (const float*)d_in[4];
    float* out = (float*)d_out;

    dim3 grid(1024 * CSPLIT), block(256);
    hipLaunchKernelGGL(roialign_chan_kernel, grid, block, 0, stream,
                       f0, f1, f2, f3, props, out);
}